// Round 8
// baseline (1904.114 us; speedup 1.0000x reference)
//
#include <hip/hip_runtime.h>
#include <hip/hip_bf16.h>
#include <math.h>

#define NBLK 6
#define NH 4
#define CCH 192
#define BB 2
#define SS 64
#define LL 256
#define DH 48
#define NP (BB*SS*LL)            // 32768 pixels
#define BUF ((size_t)NP*CCH)

typedef __attribute__((ext_vector_type(8))) short short8;
typedef __attribute__((ext_vector_type(4))) float float4v;

__device__ __forceinline__ unsigned short f2b(float f) {
    union { float f; unsigned int u; } v; v.f = f;
    unsigned int r = v.u + 0x7FFF + ((v.u >> 16) & 1);
    return (unsigned short)(r >> 16);
}
__device__ __forceinline__ float b2f(unsigned short u) {
    union { unsigned int u; float f; } v; v.u = ((unsigned int)u) << 16;
    return v.f;
}
__device__ __forceinline__ void async_lds16(const void* g, void* l) {
    __builtin_amdgcn_global_load_lds(
        (const __attribute__((address_space(1))) unsigned int*)g,
        (__attribute__((address_space(3))) unsigned int*)l, 16, 0, 0);
}

__global__ void convert_kernel(const float* __restrict__ s, unsigned short* __restrict__ d, int n) {
    int i = blockIdx.x * 256 + threadIdx.x;
    if (i < n) d[i] = f2b(s[i]);
}
__global__ void wqkv_concat(const float* __restrict__ wq, const float* __restrict__ wk,
                            const float* __restrict__ wv, unsigned short* __restrict__ d) {
    int idx = blockIdx.x * 256 + threadIdx.x;        // 12*576*192
    int wi = idx / (576 * CCH);
    int rem = idx - wi * 576 * CCH;
    int n = rem / CCH, k = rem - (rem / CCH) * CCH;
    int sg = n / 192, row = n - sg * 192;
    const float* src = (sg == 0) ? wq : (sg == 1) ? wk : wv;
    d[idx] = f2b(src[(size_t)wi * CCH * CCH + row * CCH + k]);
}
__global__ void bqkv_concat(const float* __restrict__ bq, const float* __restrict__ bk,
                            const float* __restrict__ bv, float* __restrict__ d) {
    int idx = blockIdx.x * 256 + threadIdx.x;        // 12*576
    if (idx >= NBLK * 2 * 576) return;
    int wi = idx / 576, n = idx - (idx / 576) * 576;
    int sg = n / 192, row = n - sg * 192;
    const float* src = (sg == 0) ? bq : (sg == 1) ? bk : bv;
    d[idx] = src[wi * CCH + row];
}

__global__ void gather_kernel(const int* __restrict__ tokens, const float* __restrict__ emb,
                              unsigned short* __restrict__ Eg) {
    int idx = blockIdx.x * 256 + threadIdx.x;   // NP*64
    int p = idx >> 6, c = idx & 63;
    Eg[idx] = f2b(emb[tokens[p] * 64 + c]);
}

// rotary + first LayerNorm fused
__global__ __launch_bounds__(256) void rotary_ln_kernel(const float* __restrict__ Xt, float* __restrict__ X,
                                                        unsigned short* __restrict__ Hn,
                                                        const float* __restrict__ g, const float* __restrict__ b) {
    int wave = threadIdx.x >> 6;
    int lane = threadIdx.x & 63;
    int p = blockIdx.x * 4 + wave;
    int l = p & (LL - 1);
    const float* xp = Xt + (size_t)p * CCH;
    float v[3];
    #pragma unroll
    for (int i = 0; i < 3; ++i) {
        int c = lane + i * 64;
        int j = c % 96;
        float inv = expf((float)(2 * j) * (-9.210340371976184f / 192.0f));
        float ang = (float)l * inv;
        float part = (c < 96) ? -xp[c + 96] : xp[c - 96];
        v[i] = xp[c] * cosf(ang) + part * sinf(ang);
    }
    float s = v[0] + v[1] + v[2];
    float qq = v[0] * v[0] + v[1] * v[1] + v[2] * v[2];
    #pragma unroll
    for (int off = 32; off; off >>= 1) {
        s += __shfl_xor(s, off, 64);
        qq += __shfl_xor(qq, off, 64);
    }
    float mean = s * (1.0f / 192.0f);
    float var = qq * (1.0f / 192.0f) - mean * mean;
    float r = rsqrtf(var + 1e-5f);
    float* op = X + (size_t)p * CCH;
    unsigned short* hp = Hn + (size_t)p * CCH;
    #pragma unroll
    for (int i = 0; i < 3; ++i) {
        int c = lane + i * 64;
        op[c] = v[i];
        hp[c] = f2b((v[i] - mean) * r * g[c] + b[c]);
    }
}

// ---------------- bf16 MFMA GEMM, tile MT x 192, BK=64 ----------------
// ACT: 0 none, 4 QKV-segmented. EPI: 0 bf16 store (LDS-transposed, coalesced);
// 1 fp32 store; 2 residual+LN (Hn transposed); 3 residual only.
template<int MT, int ACT, int EPI>
__global__ __launch_bounds__(256, (MT == 128) ? 2 : 3)
void mm192(const unsigned short* __restrict__ A, const unsigned short* __restrict__ W,
           const float* __restrict__ bias, unsigned short* __restrict__ Ob,
           float* __restrict__ Of, float* __restrict__ Xres, unsigned short* __restrict__ Hn,
           const float* __restrict__ lng, const float* __restrict__ lnb,
           int M, int N, int K) {
    constexpr int NI = MT / 32;
    constexpr int ACH = MT / 8;
    constexpr int TCH = ACH + 24;
    __shared__ __align__(16) unsigned char lds[TCH * 1024];
    const int tid = threadIdx.x;
    const int lane = tid & 63;
    const int w = tid >> 6;
    const int wm = w >> 1, wn = w & 1;
    const int m0 = blockIdx.y * MT;
    const int n0 = blockIdx.x * 192;
    const int q = lane >> 4;
    const int q8 = q << 3;
    const int r15 = lane & 15;

    float4v acc[NI][6];
    #pragma unroll
    for (int i = 0; i < NI; ++i)
        #pragma unroll
        for (int j = 0; j < 6; ++j)
            acc[i][j] = (float4v){0.f, 0.f, 0.f, 0.f};

    for (int k0 = 0; k0 < K; k0 += 64) {
        #pragma unroll
        for (int it = 0; it < TCH / 4; ++it) {
            int c = it * 4 + w;
            const unsigned short* gp;
            if (c < ACH) {
                int g = c >> 1, s = c & 1;
                gp = A + (size_t)(m0 + g * 16 + r15) * K + k0 + s * 32 + q8;
            } else {
                int wc = c - ACH;
                int g = wc >> 1, s = wc & 1;
                gp = W + (size_t)(n0 + g * 16 + r15) * K + k0 + s * 32 + q8;
            }
            async_lds16(gp, lds + c * 1024);
        }
        __syncthreads();
        #pragma unroll
        for (int s = 0; s < 2; ++s) {
            short8 af[NI], wf[6];
            #pragma unroll
            for (int i = 0; i < NI; ++i)
                af[i] = *(const short8*)(lds + (((wm * NI + i) * 2 + s) << 10) + lane * 16);
            #pragma unroll
            for (int j = 0; j < 6; ++j)
                wf[j] = *(const short8*)(lds + ((ACH + (wn * 6 + j) * 2 + s) << 10) + lane * 16);
            #pragma unroll
            for (int i = 0; i < NI; ++i)
                #pragma unroll
                for (int j = 0; j < 6; ++j)
                    acc[i][j] = __builtin_amdgcn_mfma_f32_16x16x32_bf16(af[i], wf[j], acc[i][j], 0, 0, 0);
        }
        __syncthreads();
    }

    const int nb = n0 + wn * 96 + r15;
    const int mb = m0 + wm * (MT / 2) + q * 4;

    if (EPI == 0) {
        // LDS-transposed coalesced bf16 store (two row-halves of MT/2=64 rows)
        unsigned short* TB = (unsigned short*)lds;
        #pragma unroll
        for (int h = 0; h < MT / 64; ++h) {
            if (wm == h) {
                #pragma unroll
                for (int j = 0; j < 6; ++j) {
                    int n = nb + j * 16;
                    float bv = bias[n];
                    #pragma unroll
                    for (int i = 0; i < NI; ++i) {
                        #pragma unroll
                        for (int r = 0; r < 4; ++r) {
                            float v = acc[i][j][r] + bv;
                            if (ACT == 4) {
                                if (n < 384) v = (v > 0.f) ? v + 1.f : expf(v);
                                if (n < 192) v *= 0.14433756729740643f;
                            }
                            TB[(i * 16 + q * 4 + r) * 200 + wn * 96 + j * 16 + r15 - n0 * 0] = f2b(v);
                        }
                    }
                }
            }
            __syncthreads();
            #pragma unroll
            for (int it = 0; it < 6; ++it) {       // 64 rows x 24 chunks / 256 thr
                int idx = tid + it * 256;
                int row = idx / 24, c = idx - (idx / 24) * 24;
                *(short8*)(Ob + (size_t)(m0 + h * 64 + row) * N + n0 + c * 8) =
                    *(const short8*)&TB[row * 200 + c * 8];
            }
            __syncthreads();
        }
    } else if (EPI == 1) {
        #pragma unroll
        for (int j = 0; j < 6; ++j) {
            int n = nb + j * 16;
            float bv = bias[n];
            #pragma unroll
            for (int i = 0; i < NI; ++i) {
                int mrow = mb + i * 16;
                #pragma unroll
                for (int r = 0; r < 4; ++r)
                    Of[(size_t)(mrow + r) * N + n] = acc[i][j][r] + bv;
            }
        }
    } else {
        #pragma unroll
        for (int j = 0; j < 6; ++j) {
            int n = nb + j * 16;
            float bv = bias[n];
            #pragma unroll
            for (int i = 0; i < NI; ++i) {
                int mrow = mb + i * 16;
                #pragma unroll
                for (int r = 0; r < 4; ++r)
                    acc[i][j][r] += bv + Xres[(size_t)(mrow + r) * 192 + n];
            }
        }
        float* lsum = (float*)lds;
        float* lsq  = lsum + 2 * MT;
        unsigned short* TB = (unsigned short*)(lds + 2048);
        #pragma unroll
        for (int i = 0; i < NI; ++i)
            #pragma unroll
            for (int r = 0; r < 4; ++r) {
                float s1 = 0.f, s2 = 0.f;
                #pragma unroll
                for (int j = 0; j < 6; ++j) {
                    float v = acc[i][j][r];
                    s1 += v; s2 += v * v;
                }
                #pragma unroll
                for (int off = 1; off < 16; off <<= 1) {
                    s1 += __shfl_xor(s1, off, 64);
                    s2 += __shfl_xor(s2, off, 64);
                }
                if (r15 == 0) {
                    int rl = wm * (MT / 2) + i * 16 + q * 4 + r;
                    lsum[rl * 2 + wn] = s1;
                    lsq[rl * 2 + wn] = s2;
                }
            }
        __syncthreads();
        #pragma unroll
        for (int i = 0; i < NI; ++i)
            #pragma unroll
            for (int r = 0; r < 4; ++r) {
                int rl = wm * (MT / 2) + i * 16 + q * 4 + r;
                int m = m0 + rl;
                float mean = (lsum[rl * 2] + lsum[rl * 2 + 1]) * (1.0f / 192.0f);
                float var = (lsq[rl * 2] + lsq[rl * 2 + 1]) * (1.0f / 192.0f) - mean * mean;
                float rstd = rsqrtf(var + 1e-5f);
                #pragma unroll
                for (int j = 0; j < 6; ++j) {
                    int n = nb + j * 16;
                    float v = acc[i][j][r];
                    Xres[(size_t)m * 192 + n] = v;
                    if (EPI == 2)
                        TB[rl * 200 + n] = f2b((v - mean) * rstd * lng[n] + lnb[n]);
                }
            }
        if (EPI == 2) {
            __syncthreads();
            #pragma unroll
            for (int it = 0; it < 6 * (MT / 64); ++it) {
                int idx = tid + it * 256;
                int row = idx / 24, c = idx - (idx / 24) * 24;
                *(short8*)(Hn + (size_t)(m0 + row) * 192 + c * 8) =
                    *(const short8*)&TB[row * 200 + c * 8];
            }
        }
    }
}

// ---------------- fused FFN: Hn/X = LN-epilogue( X + gelu(A@W1^T+b1)@W2^T + b2 ) ----------------
// 64 rows/block, 512 threads (8 waves). LDS: A 24K | W 24K | hidT 24K. Hidden never hits global.
template<bool LASTB>
__global__ __launch_bounds__(512, 4)
void ffn_fused(const unsigned short* __restrict__ A,      // [NP][192] bf16 (LN output)
               const unsigned short* __restrict__ W1,     // [768][192]
               const float* __restrict__ B1,
               const unsigned short* __restrict__ W2,     // [192][768]
               const float* __restrict__ B2,
               float* __restrict__ Xres,
               unsigned short* __restrict__ Hn,
               const float* __restrict__ lng, const float* __restrict__ lnb) {
    __shared__ __align__(16) unsigned char lds[73728];
    unsigned char* Areg = lds;            // 24 chunks (g 0..3, sk 0..5)
    unsigned char* Wreg = lds + 24576;    // 24 chunks (gn 0..11, s 0..1)
    unsigned char* Hreg = lds + 49152;    // 24 chunks, same layout as Areg
    const int tid = threadIdx.x;
    const int lane = tid & 63;
    const int w = tid >> 6;               // 0..7
    const int wm = w >> 1, wn = w & 1;    // wm: m-frag 0..3, wn: n-half
    const int m0 = blockIdx.x * 64;
    const int q = lane >> 4, q8 = q << 3, r15 = lane & 15;

    // stage A tile 64x192 once (24 chunks over 8 waves)
    #pragma unroll
    for (int it = 0; it < 3; ++it) {
        int c = it * 8 + w;
        int g = c / 6, sk = c - (c / 6) * 6;
        async_lds16(A + (size_t)(m0 + g * 16 + r15) * 192 + sk * 32 + q8, Areg + c * 1024);
    }

    float4v acc2[6];
    #pragma unroll
    for (int j = 0; j < 6; ++j) acc2[j] = (float4v){0.f, 0.f, 0.f, 0.f};

    for (int hc = 0; hc < 4; ++hc) {
        float4v acc1[6];
        #pragma unroll
        for (int j = 0; j < 6; ++j) acc1[j] = (float4v){0.f, 0.f, 0.f, 0.f};

        // GEMM1: acc1 = A @ W1[hc*192 .. +192)^T
        for (int ks = 0; ks < 3; ++ks) {
            #pragma unroll
            for (int it = 0; it < 3; ++it) {
                int c = it * 8 + w;
                int gn = c >> 1, s = c & 1;
                async_lds16(W1 + (size_t)(hc * 192 + gn * 16 + r15) * 192 + ks * 64 + s * 32 + q8,
                            Wreg + c * 1024);
            }
            __syncthreads();
            #pragma unroll
            for (int s = 0; s < 2; ++s) {
                short8 af = *(const short8*)(Areg + ((wm * 6 + ks * 2 + s) << 10) + lane * 16);
                short8 wf[6];
                #pragma unroll
                for (int j = 0; j < 6; ++j)
                    wf[j] = *(const short8*)(Wreg + ((((wn * 6 + j) * 2) + s) << 10) + lane * 16);
                #pragma unroll
                for (int j = 0; j < 6; ++j)
                    acc1[j] = __builtin_amdgcn_mfma_f32_16x16x32_bf16(af, wf[j], acc1[j], 0, 0, 0);
            }
            __syncthreads();
        }
        // gelu -> hidT (A-fragment layout); wn halves write disjoint sk chunks
        #pragma unroll
        for (int j = 0; j < 6; ++j) {
            int h = wn * 96 + j * 16 + r15;
            float bv = B1[hc * 192 + h];
            int sk = h >> 5;
            int base = (wm * 6 + sk) * 512 + ((h >> 3) & 3) * 128 + (h & 7);
            #pragma unroll
            for (int r = 0; r < 4; ++r) {
                float v = acc1[j][r] + bv;
                v = 0.5f * v * (1.0f + erff(v * 0.7071067811865475f));
                ((unsigned short*)Hreg)[base + (q * 4 + r) * 8] = f2b(v);
            }
        }
        // GEMM2: acc2 += hidT @ W2[:, hc*192 .. +192)^T
        for (int ks = 0; ks < 3; ++ks) {
            #pragma unroll
            for (int it = 0; it < 3; ++it) {
                int c = it * 8 + w;
                int gn = c >> 1, s = c & 1;
                async_lds16(W2 + (size_t)(gn * 16 + r15) * 768 + hc * 192 + ks * 64 + s * 32 + q8,
                            Wreg + c * 1024);
            }
            __syncthreads();
            #pragma unroll
            for (int s = 0; s < 2; ++s) {
                short8 af = *(const short8*)(Hreg + ((wm * 6 + ks * 2 + s) << 10) + lane * 16);
                short8 wf[6];
                #pragma unroll
                for (int j = 0; j < 6; ++j)
                    wf[j] = *(const short8*)(Wreg + ((((wn * 6 + j) * 2) + s) << 10) + lane * 16);
                #pragma unroll
                for (int j = 0; j < 6; ++j)
                    acc2[j] = __builtin_amdgcn_mfma_f32_16x16x32_bf16(af, wf[j], acc2[j], 0, 0, 0);
            }
            __syncthreads();
        }
    }

    // residual + LN epilogue
    const int nb = wn * 96 + r15;
    const int mb = m0 + wm * 16 + q * 4;
    #pragma unroll
    for (int j = 0; j < 6; ++j) {
        int n = nb + j * 16;
        float bv = B2[n];
        #pragma unroll
        for (int r = 0; r < 4; ++r)
            acc2[j][r] += bv + Xres[(size_t)(mb + r) * 192 + n];
    }
    float* lsum = (float*)lds;
    float* lsq  = lsum + 128;
    unsigned short* TB = (unsigned short*)(lds + 1024);
    #pragma unroll
    for (int r = 0; r < 4; ++r) {
        float s1 = 0.f, s2 = 0.f;
        #pragma unroll
        for (int j = 0; j < 6; ++j) {
            float v = acc2[j][r];
            s1 += v; s2 += v * v;
        }
        #pragma unroll
        for (int off = 1; off < 16; off <<= 1) {
            s1 += __shfl_xor(s1, off, 64);
            s2 += __shfl_xor(s2, off, 64);
        }
        if (r15 == 0) {
            int rl = wm * 16 + q * 4 + r;
            lsum[rl * 2 + wn] = s1;
            lsq[rl * 2 + wn] = s2;
        }
    }
    __syncthreads();
    #pragma unroll
    for (int r = 0; r < 4; ++r) {
        int rl = wm * 16 + q * 4 + r;
        int m = m0 + rl;
        float mean = (lsum[rl * 2] + lsum[rl * 2 + 1]) * (1.0f / 192.0f);
        float var = (lsq[rl * 2] + lsq[rl * 2 + 1]) * (1.0f / 192.0f) - mean * mean;
        float rstd = rsqrtf(var + 1e-5f);
        #pragma unroll
        for (int j = 0; j < 6; ++j) {
            int n = nb + j * 16;
            float v = acc2[j][r];
            Xres[(size_t)m * 192 + n] = v;
            if (!LASTB)
                TB[rl * 200 + n] = f2b((v - mean) * rstd * lng[n] + lnb[n]);
        }
    }
    if (!LASTB) {
        __syncthreads();
        #pragma unroll
        for (int it = 0; it < 3; ++it) {          // 64 rows x 24 chunks / 512 thr
            int idx = tid + it * 512;
            int row = idx / 24, c = idx - (idx / 24) * 24;
            *(short8*)(Hn + (size_t)(m0 + row) * 192 + c * 8) =
                *(const short8*)&TB[row * 200 + c * 8];
        }
    }
}

// ---------------- axial linear attention ----------------
template<int N, int MSTR>
__global__ __launch_bounds__(256) void attn_axial(const unsigned short* __restrict__ QKV,
                                                  unsigned short* __restrict__ O) {
    __shared__ unsigned short KV[32][400];
    __shared__ unsigned short kvs[4][64][72];
    const int tid = threadIdx.x;
    const int lane = tid & 63;
    const int w = tid >> 6;
    const int q = lane >> 4, r15 = lane & 15, q8 = q * 8;
    size_t base;
    if (MSTR == 1) base = (size_t)blockIdx.x * N;
    else           base = (size_t)(blockIdx.x >> 8) * 16384 + (blockIdx.x & 255);

    unsigned int* kz = (unsigned int*)&kvs[w][0][0];
    #pragma unroll
    for (int ii = 0; ii < 36; ++ii) kz[lane + ii * 64] = 0;

    short8 onesf;
    #pragma unroll
    for (int e = 0; e < 8; ++e) onesf[e] = (short)0x3F80;

    float4v kv[3][4];
    #pragma unroll
    for (int i = 0; i < 3; ++i)
        #pragma unroll
        for (int j = 0; j < 4; ++j)
            kv[i][j] = (float4v){0.f, 0.f, 0.f, 0.f};

    for (int ks = 0; ks < N; ks += 32) {
        #pragma unroll
        for (int it = 0; it < 6; ++it) {
            int cc = tid + it * 256;
            int row = cc / 48, c8 = cc - (cc / 48) * 48;
            const unsigned short* gp = QKV + ((size_t)(base + (size_t)(ks + row) * MSTR)) * 576 + 192 + c8 * 8;
            *(short8*)&KV[row][c8 * 8] = *(const short8*)gp;
        }
        __syncthreads();
        short8 af[3], bf[3];
        #pragma unroll
        for (int t = 0; t < 3; ++t) {
            #pragma unroll
            for (int j = 0; j < 8; ++j) {
                af[t][j] = (short)KV[q8 + j][w * 48 + t * 16 + r15];
                bf[t][j] = (short)KV[q8 + j][192 + w * 48 + t * 16 + r15];
            }
        }
        #pragma unroll
        for (int i = 0; i < 3; ++i) {
            #pragma unroll
            for (int j = 0; j < 3; ++j)
                kv[i][j] = __builtin_amdgcn_mfma_f32_16x16x32_bf16(af[i], bf[j], kv[i][j], 0, 0, 0);
            kv[i][3] = __builtin_amdgcn_mfma_f32_16x16x32_bf16(af[i], onesf, kv[i][3], 0, 0, 0);
        }
        __syncthreads();
    }

    #pragma unroll
    for (int i = 0; i < 3; ++i) {
        #pragma unroll
        for (int j = 0; j < 3; ++j)
            #pragma unroll
            for (int r = 0; r < 4; ++r)
                kvs[w][j * 16 + r15][i * 16 + q * 4 + r] = f2b(kv[i][j][r]);
        if (r15 == 0)
            #pragma unroll
            for (int r = 0; r < 4; ++r)
                kvs[w][48][i * 16 + q * 4 + r] = f2b(kv[i][3][r]);
    }

    short8 bkv[2][4];
    #pragma unroll
    for (int kk = 0; kk < 2; ++kk)
        #pragma unroll
        for (int t = 0; t < 4; ++t)
            bkv[kk][t] = *(const short8*)&kvs[w][t * 16 + r15][kk * 32 + q8];

    for (int mt = 0; mt < N / 16; ++mt) {
        float4v o[4];
        #pragma unroll
        for (int t = 0; t < 4; ++t) o[t] = (float4v){0.f, 0.f, 0.f, 0.f};
        #pragma unroll
        for (int kk = 0; kk < 2; ++kk) {
            const unsigned short* qp = QKV + ((size_t)(base + (size_t)(mt * 16 + r15) * MSTR)) * 576
                                       + w * 48 + kk * 32 + q8;
            short8 aq = *(const short8*)qp;
            #pragma unroll
            for (int t = 0; t < 4; ++t)
                o[t] = __builtin_amdgcn_mfma_f32_16x16x32_bf16(aq, bkv[kk][t], o[t], 0, 0, 0);
        }
        #pragma unroll
        for (int r = 0; r < 4; ++r) {
            float den = __shfl(o[3][r], q << 4);
            float z = 1.0f / (den + 1e-6f);
            int n = mt * 16 + q * 4 + r;
            unsigned short* op = O + ((size_t)(base + (size_t)n * MSTR)) * 192 + w * 48;
            #pragma unroll
            for (int t = 0; t < 3; ++t)
                op[t * 16 + r15] = f2b(o[t][r] * z);
        }
    }
}

__global__ __launch_bounds__(256) void final_kernel(const float* __restrict__ X, const float* __restrict__ pw_w,
                                                    const float* __restrict__ pw_b, float* __restrict__ out) {
    int wave = threadIdx.x >> 6;
    int lane = threadIdx.x & 63;
    int p = blockIdx.x * 4 + wave;
    const float* xp = X + (size_t)p * CCH;
    float s = xp[lane] * pw_w[lane] + xp[lane + 64] * pw_w[lane + 64] + xp[lane + 128] * pw_w[lane + 128];
    #pragma unroll
    for (int off = 32; off; off >>= 1) s += __shfl_xor(s, off, 64);
    if (lane == 0) {
        float o = s + pw_b[0];
        float e = expf(o);
        out[p] = 1.0f - 1.0f / (2.0f + e);
    }
}

extern "C" void kernel_launch(void* const* d_in, const int* in_sizes, int n_in,
                              void* d_out, int out_size, void* d_ws, size_t ws_size,
                              hipStream_t stream) {
    const int*   tokens = (const int*)  d_in[0];
    const float* emb    = (const float*)d_in[1];
    const float* proj_w = (const float*)d_in[2];
    const float* proj_b = (const float*)d_in[3];
    const float* ln_g   = (const float*)d_in[4];
    const float* ln_b   = (const float*)d_in[5];
    const float* wq     = (const float*)d_in[6];
    const float* wk     = (const float*)d_in[7];
    const float* wv     = (const float*)d_in[8];
    const float* wo     = (const float*)d_in[9];
    const float* bq     = (const float*)d_in[10];
    const float* bk     = (const float*)d_in[11];
    const float* bv     = (const float*)d_in[12];
    const float* bo     = (const float*)d_in[13];
    const float* ffn_w1 = (const float*)d_in[14];
    const float* ffn_b1 = (const float*)d_in[15];
    const float* ffn_w2 = (const float*)d_in[16];
    const float* ffn_b2 = (const float*)d_in[17];
    const float* pw_w   = (const float*)d_in[18];
    const float* pw_b   = (const float*)d_in[19];

    float* X             = (float*)d_ws;
    unsigned short* Hb   = (unsigned short*)(X + BUF);
    unsigned short* Ho   = Hb + BUF;
    unsigned short* QKVb = Ho + BUF;                     // NP x 576
    unsigned short* hid  = QKVb + 3 * BUF;               // tmp (proj only)
    unsigned short* Eg   = hid + 4 * BUF;
    unsigned short* wqkvb = Eg + (size_t)NP * 64;
    const int QKVSZ = NBLK * 2 * 576 * CCH;
    const int WSZ   = NBLK * 2 * CCH * CCH;
    const int FSZ   = NBLK * 768 * CCH;
    unsigned short* wob = wqkvb + QKVSZ;
    unsigned short* w1b = wob + WSZ;
    unsigned short* w2b = w1b + FSZ;
    unsigned short* pjb = w2b + FSZ;
    float* bqkvb = (float*)(pjb + 12288 + 32);
    float* Xt = (float*)hid;

    wqkv_concat<<<QKVSZ / 256, 256, 0, stream>>>(wq, wk, wv, wqkvb);
    bqkv_concat<<<27, 256, 0, stream>>>(bq, bk, bv, bqkvb);
    convert_kernel<<<(WSZ + 255) / 256, 256, 0, stream>>>(wo, wob, WSZ);
    convert_kernel<<<(FSZ + 255) / 256, 256, 0, stream>>>(ffn_w1, w1b, FSZ);
    convert_kernel<<<(FSZ + 255) / 256, 256, 0, stream>>>(ffn_w2, w2b, FSZ);
    convert_kernel<<<48, 256, 0, stream>>>(proj_w, pjb, 12288);

    gather_kernel<<<NP * 64 / 256, 256, 0, stream>>>(tokens, emb, Eg);
    mm192<64, 0, 1><<<dim3(1, NP / 64), 256, 0, stream>>>(Eg, pjb, proj_b, nullptr, Xt,
                                                          nullptr, nullptr, nullptr, nullptr, NP, CCH, 64);
    rotary_ln_kernel<<<NP / 4, 256, 0, stream>>>(Xt, X, Hb, ln_g, ln_b);

    for (int i = 0; i < NBLK; ++i) {
        for (int att = 0; att < 2; ++att) {
            size_t wi = (size_t)(i * 2 + att);
            const unsigned short* wqkvi = wqkvb + wi * 576 * CCH;
            const float* bqkvi = bqkvb + wi * 576;
            const unsigned short* woi = wob + wi * CCH * CCH;
            const float* boi = bo + wi * CCH;
            const float* gn  = ln_g + (size_t)(i * 3 + att + 1) * CCH;
            const float* bnn = ln_b + (size_t)(i * 3 + att + 1) * CCH;
            mm192<128, 4, 0><<<dim3(3, NP / 128), 256, 0, stream>>>(Hb, wqkvi, bqkvi, QKVb, nullptr,
                                                                    nullptr, nullptr, nullptr, nullptr, NP, 576, CCH);
            if (att == 0) attn_axial<LL, 1><<<BB * SS, 256, 0, stream>>>(QKVb, Ho);
            else          attn_axial<SS, LL><<<BB * LL, 256, 0, stream>>>(QKVb, Ho);
            mm192<64, 0, 2><<<dim3(1, NP / 64), 256, 0, stream>>>(Ho, woi, boi, nullptr, nullptr,
                                                                  X, Hb, gn, bnn, NP, CCH, CCH);
        }
        const unsigned short* w1 = w1b + (size_t)i * 768 * CCH;
        const unsigned short* w2 = w2b + (size_t)i * CCH * 768;
        const float* b1 = ffn_b1 + (size_t)i * 768;
        const float* b2 = ffn_b2 + (size_t)i * CCH;
        if (i < NBLK - 1) {
            const float* gn  = ln_g + (size_t)((i + 1) * 3) * CCH;
            const float* bnn = ln_b + (size_t)((i + 1) * 3) * CCH;
            ffn_fused<false><<<NP / 64, 512, 0, stream>>>(Hb, w1, b1, w2, b2, X, Hb, gn, bnn);
        } else {
            ffn_fused<true><<<NP / 64, 512, 0, stream>>>(Hb, w1, b1, w2, b2, X, nullptr, nullptr, nullptr);
        }
    }
    final_kernel<<<NP / 4, 256, 0, stream>>>(X, pw_w, pw_b, (float*)d_out);
}

// Round 9
// 1351.611 us; speedup vs baseline: 1.4088x; 1.4088x over previous
//
#include <hip/hip_runtime.h>
#include <hip/hip_bf16.h>
#include <math.h>

#define NBLK 6
#define NH 4
#define CCH 192
#define BB 2
#define SS 64
#define LL 256
#define DH 48
#define NP (BB*SS*LL)            // 32768 pixels
#define BUF ((size_t)NP*CCH)

typedef __attribute__((ext_vector_type(8))) short short8;
typedef __attribute__((ext_vector_type(4))) float float4v;

__device__ __forceinline__ unsigned short f2b(float f) {
    union { float f; unsigned int u; } v; v.f = f;
    unsigned int r = v.u + 0x7FFF + ((v.u >> 16) & 1);
    return (unsigned short)(r >> 16);
}
__device__ __forceinline__ float b2f(unsigned short u) {
    union { unsigned int u; float f; } v; v.u = ((unsigned int)u) << 16;
    return v.f;
}
__device__ __forceinline__ void async_lds16(const void* g, void* l) {
    __builtin_amdgcn_global_load_lds(
        (const __attribute__((address_space(1))) unsigned int*)g,
        (__attribute__((address_space(3))) unsigned int*)l, 16, 0, 0);
}

__global__ void convert_kernel(const float* __restrict__ s, unsigned short* __restrict__ d, int n) {
    int i = blockIdx.x * 256 + threadIdx.x;
    if (i < n) d[i] = f2b(s[i]);
}
__global__ void wqkv_concat(const float* __restrict__ wq, const float* __restrict__ wk,
                            const float* __restrict__ wv, unsigned short* __restrict__ d) {
    int idx = blockIdx.x * 256 + threadIdx.x;        // 12*576*192
    int wi = idx / (576 * CCH);
    int rem = idx - wi * 576 * CCH;
    int n = rem / CCH, k = rem - (rem / CCH) * CCH;
    int sg = n / 192, row = n - sg * 192;
    const float* src = (sg == 0) ? wq : (sg == 1) ? wk : wv;
    d[idx] = f2b(src[(size_t)wi * CCH * CCH + row * CCH + k]);
}
__global__ void bqkv_concat(const float* __restrict__ bq, const float* __restrict__ bk,
                            const float* __restrict__ bv, float* __restrict__ d) {
    int idx = blockIdx.x * 256 + threadIdx.x;        // 12*576
    if (idx >= NBLK * 2 * 576) return;
    int wi = idx / 576, n = idx - (idx / 576) * 576;
    int sg = n / 192, row = n - sg * 192;
    const float* src = (sg == 0) ? bq : (sg == 1) ? bk : bv;
    d[idx] = src[wi * CCH + row];
}

__global__ void gather_kernel(const int* __restrict__ tokens, const float* __restrict__ emb,
                              unsigned short* __restrict__ Eg) {
    int idx = blockIdx.x * 256 + threadIdx.x;   // NP*64
    int p = idx >> 6, c = idx & 63;
    Eg[idx] = f2b(emb[tokens[p] * 64 + c]);
}

// rotary + first LayerNorm fused
__global__ __launch_bounds__(256) void rotary_ln_kernel(const float* __restrict__ Xt, float* __restrict__ X,
                                                        unsigned short* __restrict__ Hn,
                                                        const float* __restrict__ g, const float* __restrict__ b) {
    int wave = threadIdx.x >> 6;
    int lane = threadIdx.x & 63;
    int p = blockIdx.x * 4 + wave;
    int l = p & (LL - 1);
    const float* xp = Xt + (size_t)p * CCH;
    float v[3];
    #pragma unroll
    for (int i = 0; i < 3; ++i) {
        int c = lane + i * 64;
        int j = c % 96;
        float inv = expf((float)(2 * j) * (-9.210340371976184f / 192.0f));
        float ang = (float)l * inv;
        float part = (c < 96) ? -xp[c + 96] : xp[c - 96];
        v[i] = xp[c] * cosf(ang) + part * sinf(ang);
    }
    float s = v[0] + v[1] + v[2];
    float qq = v[0] * v[0] + v[1] * v[1] + v[2] * v[2];
    #pragma unroll
    for (int off = 32; off; off >>= 1) {
        s += __shfl_xor(s, off, 64);
        qq += __shfl_xor(qq, off, 64);
    }
    float mean = s * (1.0f / 192.0f);
    float var = qq * (1.0f / 192.0f) - mean * mean;
    float r = rsqrtf(var + 1e-5f);
    float* op = X + (size_t)p * CCH;
    unsigned short* hp = Hn + (size_t)p * CCH;
    #pragma unroll
    for (int i = 0; i < 3; ++i) {
        int c = lane + i * 64;
        op[c] = v[i];
        hp[c] = f2b((v[i] - mean) * r * g[c] + b[c]);
    }
}

// ---------------- bf16 MFMA GEMM, tile MT x 192, BK=64 ----------------
// ACT: 0 none, 4 QKV-segmented. EPI: 0 bf16 store; 1 fp32 store; 2 residual+LN; 3 residual only.
// (round-6 direct-store epilogues — LDS-transpose variant regressed 2x, see R8 post-mortem)
template<int MT, int ACT, int EPI>
__global__ __launch_bounds__(256, (MT == 128) ? 2 : 3)
void mm192(const unsigned short* __restrict__ A, const unsigned short* __restrict__ W,
           const float* __restrict__ bias, unsigned short* __restrict__ Ob,
           float* __restrict__ Of, float* __restrict__ Xres, unsigned short* __restrict__ Hn,
           const float* __restrict__ lng, const float* __restrict__ lnb,
           int M, int N, int K) {
    constexpr int NI = MT / 32;
    constexpr int ACH = MT / 8;
    constexpr int TCH = ACH + 24;
    __shared__ __align__(16) unsigned char lds[TCH * 1024];
    const int tid = threadIdx.x;
    const int lane = tid & 63;
    const int w = tid >> 6;
    const int wm = w >> 1, wn = w & 1;
    const int m0 = blockIdx.y * MT;
    const int n0 = blockIdx.x * 192;
    const int q = lane >> 4;
    const int q8 = q << 3;
    const int r15 = lane & 15;

    float4v acc[NI][6];
    #pragma unroll
    for (int i = 0; i < NI; ++i)
        #pragma unroll
        for (int j = 0; j < 6; ++j)
            acc[i][j] = (float4v){0.f, 0.f, 0.f, 0.f};

    for (int k0 = 0; k0 < K; k0 += 64) {
        #pragma unroll
        for (int it = 0; it < TCH / 4; ++it) {
            int c = it * 4 + w;
            const unsigned short* gp;
            if (c < ACH) {
                int g = c >> 1, s = c & 1;
                gp = A + (size_t)(m0 + g * 16 + r15) * K + k0 + s * 32 + q8;
            } else {
                int wc = c - ACH;
                int g = wc >> 1, s = wc & 1;
                gp = W + (size_t)(n0 + g * 16 + r15) * K + k0 + s * 32 + q8;
            }
            async_lds16(gp, lds + c * 1024);
        }
        __syncthreads();
        #pragma unroll
        for (int s = 0; s < 2; ++s) {
            short8 af[NI], wf[6];
            #pragma unroll
            for (int i = 0; i < NI; ++i)
                af[i] = *(const short8*)(lds + (((wm * NI + i) * 2 + s) << 10) + lane * 16);
            #pragma unroll
            for (int j = 0; j < 6; ++j)
                wf[j] = *(const short8*)(lds + ((ACH + (wn * 6 + j) * 2 + s) << 10) + lane * 16);
            #pragma unroll
            for (int i = 0; i < NI; ++i)
                #pragma unroll
                for (int j = 0; j < 6; ++j)
                    acc[i][j] = __builtin_amdgcn_mfma_f32_16x16x32_bf16(af[i], wf[j], acc[i][j], 0, 0, 0);
        }
        __syncthreads();
    }

    const int nb = n0 + wn * 96 + r15;
    const int mb = m0 + wm * (MT / 2) + q * 4;

    if (EPI <= 1) {
        #pragma unroll
        for (int j = 0; j < 6; ++j) {
            int n = nb + j * 16;
            float bv = bias[n];
            #pragma unroll
            for (int i = 0; i < NI; ++i) {
                int mrow = mb + i * 16;
                #pragma unroll
                for (int r = 0; r < 4; ++r) {
                    float v = acc[i][j][r] + bv;
                    if (ACT == 4) {
                        if (n < 384) v = (v > 0.f) ? v + 1.f : expf(v);
                        if (n < 192) v *= 0.14433756729740643f;
                    }
                    int m = mrow + r;
                    if (EPI == 1) Of[(size_t)m * N + n] = v;
                    else          Ob[(size_t)m * N + n] = f2b(v);
                }
            }
        }
    } else {
        #pragma unroll
        for (int j = 0; j < 6; ++j) {
            int n = nb + j * 16;
            float bv = bias[n];
            #pragma unroll
            for (int i = 0; i < NI; ++i) {
                int mrow = mb + i * 16;
                #pragma unroll
                for (int r = 0; r < 4; ++r)
                    acc[i][j][r] += bv + Xres[(size_t)(mrow + r) * 192 + n];
            }
        }
        float* lsum = (float*)lds;
        float* lsq  = lsum + 2 * MT;
        #pragma unroll
        for (int i = 0; i < NI; ++i)
            #pragma unroll
            for (int r = 0; r < 4; ++r) {
                float s1 = 0.f, s2 = 0.f;
                #pragma unroll
                for (int j = 0; j < 6; ++j) {
                    float v = acc[i][j][r];
                    s1 += v; s2 += v * v;
                }
                #pragma unroll
                for (int off = 1; off < 16; off <<= 1) {
                    s1 += __shfl_xor(s1, off, 64);
                    s2 += __shfl_xor(s2, off, 64);
                }
                if (r15 == 0) {
                    int rl = wm * (MT / 2) + i * 16 + q * 4 + r;
                    lsum[rl * 2 + wn] = s1;
                    lsq[rl * 2 + wn] = s2;
                }
            }
        __syncthreads();
        #pragma unroll
        for (int i = 0; i < NI; ++i)
            #pragma unroll
            for (int r = 0; r < 4; ++r) {
                int rl = wm * (MT / 2) + i * 16 + q * 4 + r;
                int m = m0 + rl;
                float mean = (lsum[rl * 2] + lsum[rl * 2 + 1]) * (1.0f / 192.0f);
                float var = (lsq[rl * 2] + lsq[rl * 2 + 1]) * (1.0f / 192.0f) - mean * mean;
                float rstd = rsqrtf(var + 1e-5f);
                #pragma unroll
                for (int j = 0; j < 6; ++j) {
                    int n = nb + j * 16;
                    float v = acc[i][j][r];
                    Xres[(size_t)m * 192 + n] = v;
                    if (EPI == 2)
                        Hn[(size_t)m * 192 + n] = f2b((v - mean) * rstd * lng[n] + lnb[n]);
                }
            }
    }
}

// ---------------- fused FFN: Hn/X = LN-epilogue( X + gelu(A@W1^T+b1)@W2^T + b2 ) ----------------
// 64 rows/block, 256 threads. LDS: A 24K | W 24K | hidT 24K. Hidden never hits global.
// W chunks register-prefetched: loads for step t+1 issued AFTER the "Wreg ready" barrier of
// step t, so L2 latency overlaps the 12-MFMA phase (drain deferred to next bar1).
template<bool LASTB>
__global__ __launch_bounds__(256, 2)
void ffn_fused(const unsigned short* __restrict__ A,      // [NP][192] bf16 (LN output)
               const unsigned short* __restrict__ W1,     // [768][192]
               const float* __restrict__ B1,
               const unsigned short* __restrict__ W2,     // [192][768]
               const float* __restrict__ B2,
               float* __restrict__ Xres,
               unsigned short* __restrict__ Hn,
               const float* __restrict__ lng, const float* __restrict__ lnb) {
    __shared__ __align__(16) unsigned char lds[73728];
    unsigned char* Areg = lds;            // 24 chunks (g 0..3, sk 0..5)
    unsigned char* Wreg = lds + 24576;    // 24 chunks (gn 0..11, s 0..1)
    unsigned char* Hreg = lds + 49152;    // 24 chunks, same layout as Areg
    const int tid = threadIdx.x;
    const int lane = tid & 63;
    const int w = tid >> 6;
    const int wm = w >> 1, wn = w & 1;
    const int m0 = blockIdx.x * 64;
    const int q = lane >> 4, q8 = q << 3, r15 = lane & 15;

    // stage A tile 64x192 once
    #pragma unroll
    for (int it = 0; it < 6; ++it) {
        int c = it * 4 + w;
        int g = c / 6, sk = c - (c / 6) * 6;
        async_lds16(A + (size_t)(m0 + g * 16 + r15) * 192 + sk * 32 + q8, Areg + c * 1024);
    }

    // prefetch W chunks for step t=0 (hc=0, GEMM1 ks=0)
    short8 pre[6];
    #pragma unroll
    for (int it = 0; it < 6; ++it) {
        int c = it * 4 + w, gn = c >> 1, s = c & 1;
        pre[it] = *(const short8*)(W1 + (size_t)(gn * 16 + r15) * 192 + s * 32 + q8);
    }

    float4v acc2[2][6];
    #pragma unroll
    for (int i = 0; i < 2; ++i)
        #pragma unroll
        for (int j = 0; j < 6; ++j)
            acc2[i][j] = (float4v){0.f, 0.f, 0.f, 0.f};

    for (int hc = 0; hc < 4; ++hc) {
        float4v acc1[2][6];
        #pragma unroll
        for (int i = 0; i < 2; ++i)
            #pragma unroll
            for (int j = 0; j < 6; ++j)
                acc1[i][j] = (float4v){0.f, 0.f, 0.f, 0.f};

        #pragma unroll
        for (int u = 0; u < 6; ++u) {
            __syncthreads();                       // prev MFMA done reading Wreg
            #pragma unroll
            for (int it = 0; it < 6; ++it)
                *(short8*)(Wreg + ((it * 4 + w) << 10) + lane * 16) = pre[it];
            __syncthreads();                       // Wreg ready (u==3: Hreg also ready)
            // issue prefetch for next step — overlaps the MFMA phase below
            int t = hc * 6 + u + 1;
            if (t < 24) {
                int nhc = t / 6, nu = t - nhc * 6;
                #pragma unroll
                for (int it = 0; it < 6; ++it) {
                    int c = it * 4 + w, gn = c >> 1, s = c & 1;
                    const unsigned short* gp = (nu < 3)
                        ? W1 + (size_t)(nhc * 192 + gn * 16 + r15) * 192 + nu * 64 + s * 32 + q8
                        : W2 + (size_t)(gn * 16 + r15) * 768 + nhc * 192 + (nu - 3) * 64 + s * 32 + q8;
                    pre[it] = *(const short8*)gp;
                }
            }
            #pragma unroll
            for (int s = 0; s < 2; ++s) {
                short8 wf[6], af[2];
                #pragma unroll
                for (int j = 0; j < 6; ++j)
                    wf[j] = *(const short8*)(Wreg + (((wn * 6 + j) * 2 + s) << 10) + lane * 16);
                if (u < 3) {
                    #pragma unroll
                    for (int i = 0; i < 2; ++i)
                        af[i] = *(const short8*)(Areg + (((wm * 2 + i) * 6 + u * 2 + s) << 10) + lane * 16);
                    #pragma unroll
                    for (int i = 0; i < 2; ++i)
                        #pragma unroll
                        for (int j = 0; j < 6; ++j)
                            acc1[i][j] = __builtin_amdgcn_mfma_f32_16x16x32_bf16(af[i], wf[j], acc1[i][j], 0, 0, 0);
                } else {
                    #pragma unroll
                    for (int i = 0; i < 2; ++i)
                        af[i] = *(const short8*)(Hreg + (((wm * 2 + i) * 6 + (u - 3) * 2 + s) << 10) + lane * 16);
                    #pragma unroll
                    for (int i = 0; i < 2; ++i)
                        #pragma unroll
                        for (int j = 0; j < 6; ++j)
                            acc2[i][j] = __builtin_amdgcn_mfma_f32_16x16x32_bf16(af[i], wf[j], acc2[i][j], 0, 0, 0);
                }
            }
            if (u == 2) {
                // gelu -> hidT (A-fragment layout); next read is after u=3's barriers
                #pragma unroll
                for (int i = 0; i < 2; ++i) {
                    int g = wm * 2 + i;
                    #pragma unroll
                    for (int j = 0; j < 6; ++j) {
                        int h = wn * 96 + j * 16 + r15;
                        float bv = B1[hc * 192 + h];
                        int sk = h >> 5;
                        int base = (g * 6 + sk) * 512 + ((h >> 3) & 3) * 128 + (h & 7);
                        #pragma unroll
                        for (int r = 0; r < 4; ++r) {
                            float v = acc1[i][j][r] + bv;
                            v = 0.5f * v * (1.0f + erff(v * 0.7071067811865475f));
                            ((unsigned short*)Hreg)[base + (q * 4 + r) * 8] = f2b(v);
                        }
                    }
                }
            }
        }
    }

    // residual + LN epilogue (round-6 direct stores)
    const int nb = wn * 96 + r15;
    const int mb = m0 + wm * 32 + q * 4;
    #pragma unroll
    for (int j = 0; j < 6; ++j) {
        int n = nb + j * 16;
        float bv = B2[n];
        #pragma unroll
        for (int i = 0; i < 2; ++i) {
            int mrow = mb + i * 16;
            #pragma unroll
            for (int r = 0; r < 4; ++r)
                acc2[i][j][r] += bv + Xres[(size_t)(mrow + r) * 192 + n];
        }
    }
    __syncthreads();
    float* lsum = (float*)lds;
    float* lsq  = lsum + 128;
    #pragma unroll
    for (int i = 0; i < 2; ++i)
        #pragma unroll
        for (int r = 0; r < 4; ++r) {
            float s1 = 0.f, s2 = 0.f;
            #pragma unroll
            for (int j = 0; j < 6; ++j) {
                float v = acc2[i][j][r];
                s1 += v; s2 += v * v;
            }
            #pragma unroll
            for (int off = 1; off < 16; off <<= 1) {
                s1 += __shfl_xor(s1, off, 64);
                s2 += __shfl_xor(s2, off, 64);
            }
            if (r15 == 0) {
                int rl = wm * 32 + i * 16 + q * 4 + r;
                lsum[rl * 2 + wn] = s1;
                lsq[rl * 2 + wn] = s2;
            }
        }
    __syncthreads();
    #pragma unroll
    for (int i = 0; i < 2; ++i)
        #pragma unroll
        for (int r = 0; r < 4; ++r) {
            int rl = wm * 32 + i * 16 + q * 4 + r;
            int m = m0 + rl;
            float mean = (lsum[rl * 2] + lsum[rl * 2 + 1]) * (1.0f / 192.0f);
            float var = (lsq[rl * 2] + lsq[rl * 2 + 1]) * (1.0f / 192.0f) - mean * mean;
            float rstd = rsqrtf(var + 1e-5f);
            #pragma unroll
            for (int j = 0; j < 6; ++j) {
                int n = nb + j * 16;
                float v = acc2[i][j][r];
                Xres[(size_t)m * 192 + n] = v;
                if (!LASTB)
                    Hn[(size_t)m * 192 + n] = f2b((v - mean) * rstd * lng[n] + lnb[n]);
            }
        }
}

// ---------------- axial linear attention ----------------
template<int N, int MSTR>
__global__ __launch_bounds__(256) void attn_axial(const unsigned short* __restrict__ QKV,
                                                  unsigned short* __restrict__ O) {
    __shared__ unsigned short KV[32][400];
    __shared__ unsigned short kvs[4][64][72];
    const int tid = threadIdx.x;
    const int lane = tid & 63;
    const int w = tid >> 6;
    const int q = lane >> 4, r15 = lane & 15, q8 = q * 8;
    size_t base;
    if (MSTR == 1) base = (size_t)blockIdx.x * N;
    else           base = (size_t)(blockIdx.x >> 8) * 16384 + (blockIdx.x & 255);

    unsigned int* kz = (unsigned int*)&kvs[w][0][0];
    #pragma unroll
    for (int ii = 0; ii < 36; ++ii) kz[lane + ii * 64] = 0;

    short8 onesf;
    #pragma unroll
    for (int e = 0; e < 8; ++e) onesf[e] = (short)0x3F80;

    float4v kv[3][4];
    #pragma unroll
    for (int i = 0; i < 3; ++i)
        #pragma unroll
        for (int j = 0; j < 4; ++j)
            kv[i][j] = (float4v){0.f, 0.f, 0.f, 0.f};

    for (int ks = 0; ks < N; ks += 32) {
        #pragma unroll
        for (int it = 0; it < 6; ++it) {
            int cc = tid + it * 256;
            int row = cc / 48, c8 = cc - (cc / 48) * 48;
            const unsigned short* gp = QKV + ((size_t)(base + (size_t)(ks + row) * MSTR)) * 576 + 192 + c8 * 8;
            *(short8*)&KV[row][c8 * 8] = *(const short8*)gp;
        }
        __syncthreads();
        short8 af[3], bf[3];
        #pragma unroll
        for (int t = 0; t < 3; ++t) {
            #pragma unroll
            for (int j = 0; j < 8; ++j) {
                af[t][j] = (short)KV[q8 + j][w * 48 + t * 16 + r15];
                bf[t][j] = (short)KV[q8 + j][192 + w * 48 + t * 16 + r15];
            }
        }
        #pragma unroll
        for (int i = 0; i < 3; ++i) {
            #pragma unroll
            for (int j = 0; j < 3; ++j)
                kv[i][j] = __builtin_amdgcn_mfma_f32_16x16x32_bf16(af[i], bf[j], kv[i][j], 0, 0, 0);
            kv[i][3] = __builtin_amdgcn_mfma_f32_16x16x32_bf16(af[i], onesf, kv[i][3], 0, 0, 0);
        }
        __syncthreads();
    }

    #pragma unroll
    for (int i = 0; i < 3; ++i) {
        #pragma unroll
        for (int j = 0; j < 3; ++j)
            #pragma unroll
            for (int r = 0; r < 4; ++r)
                kvs[w][j * 16 + r15][i * 16 + q * 4 + r] = f2b(kv[i][j][r]);
        if (r15 == 0)
            #pragma unroll
            for (int r = 0; r < 4; ++r)
                kvs[w][48][i * 16 + q * 4 + r] = f2b(kv[i][3][r]);
    }

    short8 bkv[2][4];
    #pragma unroll
    for (int kk = 0; kk < 2; ++kk)
        #pragma unroll
        for (int t = 0; t < 4; ++t)
            bkv[kk][t] = *(const short8*)&kvs[w][t * 16 + r15][kk * 32 + q8];

    for (int mt = 0; mt < N / 16; ++mt) {
        float4v o[4];
        #pragma unroll
        for (int t = 0; t < 4; ++t) o[t] = (float4v){0.f, 0.f, 0.f, 0.f};
        #pragma unroll
        for (int kk = 0; kk < 2; ++kk) {
            const unsigned short* qp = QKV + ((size_t)(base + (size_t)(mt * 16 + r15) * MSTR)) * 576
                                       + w * 48 + kk * 32 + q8;
            short8 aq = *(const short8*)qp;
            #pragma unroll
            for (int t = 0; t < 4; ++t)
                o[t] = __builtin_amdgcn_mfma_f32_16x16x32_bf16(aq, bkv[kk][t], o[t], 0, 0, 0);
        }
        #pragma unroll
        for (int r = 0; r < 4; ++r) {
            float den = __shfl(o[3][r], q << 4);
            float z = 1.0f / (den + 1e-6f);
            int n = mt * 16 + q * 4 + r;
            unsigned short* op = O + ((size_t)(base + (size_t)n * MSTR)) * 192 + w * 48;
            #pragma unroll
            for (int t = 0; t < 3; ++t)
                op[t * 16 + r15] = f2b(o[t][r] * z);
        }
    }
}

__global__ __launch_bounds__(256) void final_kernel(const float* __restrict__ X, const float* __restrict__ pw_w,
                                                    const float* __restrict__ pw_b, float* __restrict__ out) {
    int wave = threadIdx.x >> 6;
    int lane = threadIdx.x & 63;
    int p = blockIdx.x * 4 + wave;
    const float* xp = X + (size_t)p * CCH;
    float s = xp[lane] * pw_w[lane] + xp[lane + 64] * pw_w[lane + 64] + xp[lane + 128] * pw_w[lane + 128];
    #pragma unroll
    for (int off = 32; off; off >>= 1) s += __shfl_xor(s, off, 64);
    if (lane == 0) {
        float o = s + pw_b[0];
        float e = expf(o);
        out[p] = 1.0f - 1.0f / (2.0f + e);
    }
}

extern "C" void kernel_launch(void* const* d_in, const int* in_sizes, int n_in,
                              void* d_out, int out_size, void* d_ws, size_t ws_size,
                              hipStream_t stream) {
    const int*   tokens = (const int*)  d_in[0];
    const float* emb    = (const float*)d_in[1];
    const float* proj_w = (const float*)d_in[2];
    const float* proj_b = (const float*)d_in[3];
    const float* ln_g   = (const float*)d_in[4];
    const float* ln_b   = (const float*)d_in[5];
    const float* wq     = (const float*)d_in[6];
    const float* wk     = (const float*)d_in[7];
    const float* wv     = (const float*)d_in[8];
    const float* wo     = (const float*)d_in[9];
    const float* bq     = (const float*)d_in[10];
    const float* bk     = (const float*)d_in[11];
    const float* bv     = (const float*)d_in[12];
    const float* bo     = (const float*)d_in[13];
    const float* ffn_w1 = (const float*)d_in[14];
    const float* ffn_b1 = (const float*)d_in[15];
    const float* ffn_w2 = (const float*)d_in[16];
    const float* ffn_b2 = (const float*)d_in[17];
    const float* pw_w   = (const float*)d_in[18];
    const float* pw_b   = (const float*)d_in[19];

    float* X             = (float*)d_ws;
    unsigned short* Hb   = (unsigned short*)(X + BUF);
    unsigned short* Ho   = Hb + BUF;
    unsigned short* QKVb = Ho + BUF;                     // NP x 576
    unsigned short* hid  = QKVb + 3 * BUF;               // tmp (proj only)
    unsigned short* Eg   = hid + 4 * BUF;
    unsigned short* wqkvb = Eg + (size_t)NP * 64;
    const int QKVSZ = NBLK * 2 * 576 * CCH;
    const int WSZ   = NBLK * 2 * CCH * CCH;
    const int FSZ   = NBLK * 768 * CCH;
    unsigned short* wob = wqkvb + QKVSZ;
    unsigned short* w1b = wob + WSZ;
    unsigned short* w2b = w1b + FSZ;
    unsigned short* pjb = w2b + FSZ;
    float* bqkvb = (float*)(pjb + 12288 + 32);
    float* Xt = (float*)hid;

    wqkv_concat<<<QKVSZ / 256, 256, 0, stream>>>(wq, wk, wv, wqkvb);
    bqkv_concat<<<27, 256, 0, stream>>>(bq, bk, bv, bqkvb);
    convert_kernel<<<(WSZ + 255) / 256, 256, 0, stream>>>(wo, wob, WSZ);
    convert_kernel<<<(FSZ + 255) / 256, 256, 0, stream>>>(ffn_w1, w1b, FSZ);
    convert_kernel<<<(FSZ + 255) / 256, 256, 0, stream>>>(ffn_w2, w2b, FSZ);
    convert_kernel<<<48, 256, 0, stream>>>(proj_w, pjb, 12288);

    gather_kernel<<<NP * 64 / 256, 256, 0, stream>>>(tokens, emb, Eg);
    mm192<64, 0, 1><<<dim3(1, NP / 64), 256, 0, stream>>>(Eg, pjb, proj_b, nullptr, Xt,
                                                          nullptr, nullptr, nullptr, nullptr, NP, CCH, 64);
    rotary_ln_kernel<<<NP / 4, 256, 0, stream>>>(Xt, X, Hb, ln_g, ln_b);

    for (int i = 0; i < NBLK; ++i) {
        for (int att = 0; att < 2; ++att) {
            size_t wi = (size_t)(i * 2 + att);
            const unsigned short* wqkvi = wqkvb + wi * 576 * CCH;
            const float* bqkvi = bqkvb + wi * 576;
            const unsigned short* woi = wob + wi * CCH * CCH;
            const float* boi = bo + wi * CCH;
            const float* gn  = ln_g + (size_t)(i * 3 + att + 1) * CCH;
            const float* bnn = ln_b + (size_t)(i * 3 + att + 1) * CCH;
            mm192<128, 4, 0><<<dim3(3, NP / 128), 256, 0, stream>>>(Hb, wqkvi, bqkvi, QKVb, nullptr,
                                                                    nullptr, nullptr, nullptr, nullptr, NP, 576, CCH);
            if (att == 0) attn_axial<LL, 1><<<BB * SS, 256, 0, stream>>>(QKVb, Ho);
            else          attn_axial<SS, LL><<<BB * LL, 256, 0, stream>>>(QKVb, Ho);
            mm192<64, 0, 2><<<dim3(1, NP / 64), 256, 0, stream>>>(Ho, woi, boi, nullptr, nullptr,
                                                                  X, Hb, gn, bnn, NP, CCH, CCH);
        }
        const unsigned short* w1 = w1b + (size_t)i * 768 * CCH;
        const unsigned short* w2 = w2b + (size_t)i * CCH * 768;
        const float* b1 = ffn_b1 + (size_t)i * 768;
        const float* b2 = ffn_b2 + (size_t)i * CCH;
        if (i < NBLK - 1) {
            const float* gn  = ln_g + (size_t)((i + 1) * 3) * CCH;
            const float* bnn = ln_b + (size_t)((i + 1) * 3) * CCH;
            ffn_fused<false><<<NP / 64, 256, 0, stream>>>(Hb, w1, b1, w2, b2, X, Hb, gn, bnn);
        } else {
            ffn_fused<true><<<NP / 64, 256, 0, stream>>>(Hb, w1, b1, w2, b2, X, nullptr, nullptr, nullptr);
        }
    }
    final_kernel<<<NP / 4, 256, 0, stream>>>(X, pw_w, pw_b, (float*)d_out);
}